// Round 6
// baseline (233.901 us; speedup 1.0000x reference)
//
#include <hip/hip_runtime.h>
#include <stdint.h>

#define BLOCK 256
#define ITEMS 8
#define TILE (BLOCK * ITEMS)   // 2048 elements per tile
#define WPB (TILE / 64)        // 32 bitmask words per tile
#define MAXSEG 64
#define CHUNK 64               // tiles per count-chunk
#define NCMAX 128              // supports nb <= 8192 (n <= 16.7M)
#define SEGSTRIDE 16           // u64s per seg_packed slot = 128B (own line, R4 lesson)
#define CHSTRIDE 32            // ints per chunk_sums slot = 128B (own line)
#define THRESH 0.1f

typedef unsigned long long u64;

// Coherent-point accessors. ALL data crossing the grid barrier is written and
// read via device-scope atomics (they execute at the coherent point past the
// non-coherent per-XCD L2s), so NO __threadfence / L2 writeback is ever
// needed (R1: per-block threadfence = buffer_wbl2, ~200us of stall).
__device__ __forceinline__ u64 aload64(u64* p) { return atomicAdd(p, 0ull); }
__device__ __forceinline__ int aload32(int* p) { return atomicAdd(p, 0); }

__device__ __forceinline__ int find_seg(const int* rs, int n_seg, int i) {
    int lo = 0, hi = n_seg;
    while (hi - lo > 1) {
        int mid = (lo + hi) >> 1;
        if (rs[mid] <= i) lo = mid; else hi = mid;
    }
    return lo;
}

// Grid barrier: relaxed atomic counter (init -1 by 0xFF memset), cumulative
// targets. Ordering: __syncthreads() drains vmcnt(0) per wave before
// s_barrier (compiler-guaranteed), so every prior atomic has completed at the
// coherent point before thread 0 publishes arrival. Consumers' post-spin
// atomic loads fetch from the same coherent point -> no fences anywhere.
// Co-residency of all G blocks is guaranteed by host-side occupancy sizing.
__device__ __forceinline__ void grid_bar(int* ctr, int target) {
    __syncthreads();
    if (threadIdx.x == 0) {
        __asm__ volatile("s_waitcnt vmcnt(0)" ::: "memory");
        atomicAdd(ctr, 1);
        while (aload32(ctr) < target) __builtin_amdgcn_s_sleep(8);
    }
    __syncthreads();
}

// Wave-cooperative global keep-prefix at element idx (phase 3).
// chq[chunk] (LDS, exclusive chunk prefix) + in-chunk tile counts (<=63
// atomic loads) + in-tile word popcounts (<=31 atomic u64 loads) + partial
// word. Valid on lane 0.
__device__ __forceinline__ int wpa(int idx, const int* chq, int* bc,
                                   u64* bm, int lane) {
    int t = idx / TILE, c = t / CHUNK;
    int v = 0;
    int j = c * CHUNK + lane;
    if (j < t) v += aload32(&bc[j]);
    int wq = idx >> 6;
    int w = t * WPB + lane;
    if (lane < WPB && w < wq) v += __popcll(aload64(&bm[w]));
    if (lane == 0 && (idx & 63)) v += __popcll(aload64(&bm[wq]) & ((1ull << (idx & 63)) - 1));
    for (int o = 32; o > 0; o >>= 1) v += __shfl_down(v, o, 64);
    return chq[c] + v;
}

// Single persistent kernel: phase1 (scan+bitmask+counts+seg-min) -> barrier ->
// phase2 (min-tie fixup, 64 blocks active) -> barrier -> phase3 (self-scan +
// outputs). Phase bodies are the proven R5 bodies with cross-barrier data
// moved to atomics.
__global__ __launch_bounds__(BLOCK) void k_fused(const float* __restrict__ score,
        const int* __restrict__ row_splits, int n_seg, int n, int nb,
        int nwords, int nchunk, int M, int G,
        u64* partial_val, int* partial_seg, u64* bitmask, int* block_counts,
        u64* seg_packed, int* chunk_sums, int* ctr,
        int* __restrict__ sel_out, int* __restrict__ back_out,
        int* __restrict__ newrs_out) {
    __shared__ int rs[MAXSEG + 1];
    __shared__ u64 wval[8];
    __shared__ int wseg[8];
    __shared__ int wsum[4];
    __shared__ int nmatch;
    __shared__ int mlist[64];
    __shared__ u64 swords[WPB];
    __shared__ int wpre[WPB];
    __shared__ int shead[8];   // bval, s0, s1, tot, bo, rep0, rep1
    __shared__ int qidx[4];
    __shared__ int chq[NCMAX];
    __shared__ alignas(16) int skel[TILE + 8];

    for (int j = threadIdx.x; j <= n_seg; j += BLOCK) rs[j] = row_splits[j];
    __syncthreads();
    int lane = threadIdx.x & 63, wv = threadIdx.x >> 6;

    // ---------------- phase 1 ----------------
    for (int t = blockIdx.x; t < nb; t += G) {
        int wbase = t * TILE + wv * 512;
        u64 m0 = ~0ull, m1 = ~0ull;
        int sf = -1, sl = -1, cnt = 0;
        if (wbase < n) {   // wave-uniform
            int wend = min(n, wbase + 512) - 1;
            sf = find_seg(rs, n_seg, wbase);
            sl = find_seg(rs, n_seg, wend);
            int bval = (sl != sf) ? rs[sf + 1] : 0x7FFFFFFF;
            int tbase = wbase + lane * 8;
            unsigned int kbyte = 0;
            if (tbase < n) {
                float v[8];
                if (tbase + 8 <= n) {
                    float4 f0 = *(const float4*)(score + tbase);
                    float4 f1 = *(const float4*)(score + tbase + 4);
                    v[0]=f0.x; v[1]=f0.y; v[2]=f0.z; v[3]=f0.w;
                    v[4]=f1.x; v[5]=f1.y; v[6]=f1.z; v[7]=f1.w;
                } else {
                    for (int j = 0; j < 8; j++) v[j] = (tbase + j < n) ? score[tbase + j] : 1.0f;
                }
                #pragma unroll
                for (int j = 0; j < 8; j++) {
                    int i = tbase + j;
                    if (i < n) {
                        u64 p = ((u64)__float_as_uint(v[j]) << 32) | (unsigned int)i;
                        if (i < bval) m0 = min(m0, p); else m1 = min(m1, p);
                        if (v[j] > THRESH) kbyte |= 1u << j;
                    }
                }
                cnt = __popc(kbyte);
            }
            u64 acc = ((u64)kbyte) << (8 * (lane & 7));
            acc |= __shfl_xor((unsigned long long)acc, 1, 64);
            acc |= __shfl_xor((unsigned long long)acc, 2, 64);
            acc |= __shfl_xor((unsigned long long)acc, 4, 64);
            int src = (lane < 8) ? (8 * lane) : lane;
            u64 myword = __shfl((unsigned long long)acc, src, 64);
            for (int o = 32; o > 0; o >>= 1) {
                m0 = min(m0, (u64)__shfl_down((unsigned long long)m0, o, 64));
                m1 = min(m1, (u64)__shfl_down((unsigned long long)m1, o, 64));
                cnt += __shfl_down(cnt, o, 64);
            }
            if (lane < 8) {
                int w = (wbase >> 6) + lane;
                if (w < nwords) atomicExch(&bitmask[w], myword);   // coherent publish
            }
        }
        if (lane == 0) {
            wval[2 * wv] = m0;     wseg[2 * wv] = sf;
            wval[2 * wv + 1] = m1; wseg[2 * wv + 1] = (sl != sf) ? sl : -1;
            wsum[wv] = (wbase < n) ? cnt : 0;
        }
        __syncthreads();
        if (threadIdx.x == 0) {
            int base = t * TILE;
            int endi = min(n, base + TILE) - 1;
            int s0 = find_seg(rs, n_seg, base);
            int s1 = find_seg(rs, n_seg, endi);
            u64 o0 = ~0ull, o1 = ~0ull;
            for (int k = 0; k < 8; k++) {
                if (wseg[k] == s0) o0 = min(o0, wval[k]);
                else if (wseg[k] == s1) o1 = min(o1, wval[k]);
            }
            atomicExch(&partial_val[2 * t], o0);
            atomicExch(&partial_seg[2 * t], s0);
            atomicExch(&partial_val[2 * t + 1], o1);
            atomicExch(&partial_seg[2 * t + 1], (s1 != s0) ? s1 : -1);
            int bc = wsum[0] + wsum[1] + wsum[2] + wsum[3];
            atomicExch(&block_counts[t], bc);
            atomicAdd(&chunk_sums[CHSTRIDE * (t / CHUNK)], bc);
            atomicMin(&seg_packed[SEGSTRIDE * s0], o0);
            if (s1 != s0) atomicMin(&seg_packed[SEGSTRIDE * s1], o1);
        }
        __syncthreads();   // wval/wsum reuse next iteration
    }
    grid_bar(ctr, G - 1);

    // ---------------- phase 2 (blocks < n_seg) ----------------
    if ((int)blockIdx.x < n_seg) {
        int s = blockIdx.x;
        int lo = rs[s], hi = rs[s + 1];
        if (threadIdx.x == 0) nmatch = 0;
        __syncthreads();
        if (hi > lo) {
            u64 sp = aload64(&seg_packed[SEGSTRIDE * s]);
            unsigned int smb = (unsigned int)(sp >> 32);
            if (sp != ~0ull && __uint_as_float(smb) <= THRESH) {
                int e0 = 2 * (lo / TILE), e1 = 2 * ((hi - 1) / TILE) + 1;
                for (int e = e0 + threadIdx.x; e <= e1; e += BLOCK) {
                    if (aload32(&partial_seg[e]) == s &&
                        (unsigned int)(aload64(&partial_val[e]) >> 32) == smb) {
                        int k = atomicAdd(&nmatch, 1);
                        if (k < 64) mlist[k] = e >> 1;
                    }
                }
                __syncthreads();
                int nm = min(nmatch, 64);
                for (int k = 0; k < nm; k++) {
                    int b = mlist[k];
                    int rlo = max(b * TILE, lo);
                    int rhi = min(min((b + 1) * TILE, n), hi);
                    int c = 0;
                    for (int i = rlo + threadIdx.x; i < rhi; i += BLOCK) {
                        if (__float_as_uint(score[i]) == smb) {   // input: plain read ok
                            atomicOr(&bitmask[i >> 6], 1ull << (i & 63));
                            c++;
                        }
                    }
                    for (int o = 32; o > 0; o >>= 1) c += __shfl_down(c, o, 64);
                    if (lane == 0 && c) {
                        atomicAdd(&block_counts[b], c);
                        atomicAdd(&chunk_sums[CHSTRIDE * (b / CHUNK)], c);
                    }
                }
            }
        }
    }
    grid_bar(ctr, 2 * G - 1);

    // ---------------- phase 3 ----------------
    // per-block chunk prefix (once): wave 0 loads+scans nchunk sums
    if (wv == 0) {
        int c0 = 2 * lane, c1 = 2 * lane + 1;
        int a  = (c0 < nchunk) ? aload32(&chunk_sums[CHSTRIDE * c0]) + 1 : 0;
        int b2 = (c1 < nchunk) ? aload32(&chunk_sums[CHSTRIDE * c1]) + 1 : 0;
        int ps = a + b2, incl = ps;
        for (int o = 1; o < 64; o <<= 1) {
            int tv = __shfl_up(incl, o, 64);
            if (lane >= o) incl += tv;
        }
        int excl = incl - ps;
        if (c0 < nchunk) chq[c0] = excl;
        if (c1 < nchunk) chq[c1] = excl + a;
    }
    __syncthreads();

    for (int t = blockIdx.x; t < nb; t += G) {
        int base = t * TILE;
        int lim = min(TILE, n - base);
        int nw = (lim + 63) >> 6;
        for (int j = threadIdx.x; j < nw; j += BLOCK)
            swords[j] = aload64(&bitmask[(base >> 6) + j]);   // post-fix, coherent
        __syncthreads();
        if (threadIdx.x == 0) {
            int s0 = find_seg(rs, n_seg, base);
            int s1 = find_seg(rs, n_seg, base + lim - 1);
            shead[0] = (s1 != s0) ? rs[s0 + 1] : 0x7FFFFFFF;
            shead[1] = s0;
            shead[2] = s1;
            unsigned int u0 = (unsigned int)(aload64(&seg_packed[SEGSTRIDE * s0]) & 0xFFFFFFFFu);
            unsigned int u1 = (unsigned int)(aload64(&seg_packed[SEGSTRIDE * s1]) & 0xFFFFFFFFu);
            qidx[1] = (u0 < (unsigned int)n) ? (int)u0 : -1;
            qidx[2] = (s1 != s0) ? ((u1 < (unsigned int)n) ? (int)u1 : -1) : qidx[1];
        } else if (threadIdx.x == 64) {
            int acc = 0;
            for (int k = 0; k < nw; k++) { wpre[k] = acc; acc += __popcll(swords[k]); }
            shead[3] = acc;
        }
        __syncthreads();
        if (wv == 0) {
            int r = wpa(base, chq, block_counts, bitmask, lane);
            if (lane == 0) shead[4] = r;                       // block offset
        } else if (wv == 1 || wv == 2) {
            int qi = qidx[wv];
            int r;
            if (qi < 0) r = M;
            else r = wpa(qi, chq, block_counts, bitmask, lane);
            if (lane == 0) shead[4 + wv] = r;                  // rep0 / rep1
        }
        __syncthreads();
        int bval = shead[0], tot = shead[3], bo = shead[4];
        int rep0 = shead[5], rep1 = shead[6];
        // newrs boundaries inside this tile (own LDS words + bo)
        if (threadIdx.x < n_seg) {
            int u = rs[threadIdx.x];
            if (u >= base && u < base + lim) {
                int j = u - base, widx = j >> 6;
                int r = bo + wpre[widx] +
                        ((j & 63) ? __popcll(swords[widx] & ((1ull << (j & 63)) - 1)) : 0);
                newrs_out[threadIdx.x] = r;
            }
        }
        if (t == nb - 1 && threadIdx.x == 0) newrs_out[n_seg] = M;

        // phases for aligned int4 stores
        int st_b = (int)((4 - ((((uintptr_t)(back_out + base)) >> 2) & 3)) & 3);
        if (st_b > lim) st_b = lim;
        int st_s = (int)((4 - ((((uintptr_t)(sel_out + bo)) >> 2) & 3)) & 3);
        if (st_s > tot) st_s = tot;
        int selpad = 4 - st_s;

        int ngroups = (lim - st_b) >> 2;
        for (int g = threadIdx.x; g < ngroups; g += BLOCK) {
            int j0 = st_b + 4 * g;
            int vals[4];
            #pragma unroll
            for (int k = 0; k < 4; k++) {
                int j = j0 + k;
                int widx = j >> 6, r = j & 63;
                u64 w = swords[widx];
                int i = base + j;
                if ((w >> r) & 1) {
                    int pos = bo + wpre[widx] + __popcll(w & ((1ull << r) - 1));
                    vals[k] = pos;
                    skel[pos - bo + selpad] = i;
                } else {
                    vals[k] = (i >= bval) ? rep1 : rep0;
                }
            }
            *(int4*)(back_out + base + j0) = make_int4(vals[0], vals[1], vals[2], vals[3]);
        }
        for (int j = threadIdx.x; j < st_b; j += BLOCK) {
            int widx = j >> 6, r = j & 63;
            u64 w = swords[widx];
            int i = base + j, val;
            if ((w >> r) & 1) {
                int pos = bo + wpre[widx] + __popcll(w & ((1ull << r) - 1));
                val = pos;
                skel[pos - bo + selpad] = i;
            } else val = (i >= bval) ? rep1 : rep0;
            back_out[i] = val;
        }
        for (int j = st_b + 4 * ngroups + threadIdx.x; j < lim; j += BLOCK) {
            int widx = j >> 6, r = j & 63;
            u64 w = swords[widx];
            int i = base + j, val;
            if ((w >> r) & 1) {
                int pos = bo + wpre[widx] + __popcll(w & ((1ull << r) - 1));
                val = pos;
                skel[pos - bo + selpad] = i;
            } else val = (i >= bval) ? rep1 : rep0;
            back_out[i] = val;
        }
        __syncthreads();
        int nvg = (tot - st_s) >> 2;
        for (int g = threadIdx.x; g < nvg; g += BLOCK) {
            int4 v = *(const int4*)&skel[4 + 4 * g];
            *(int4*)(sel_out + bo + st_s + 4 * g) = v;
        }
        for (int j = threadIdx.x; j < st_s; j += BLOCK) sel_out[bo + j] = skel[j + selpad];
        for (int j = st_s + 4 * nvg + threadIdx.x; j < tot; j += BLOCK) sel_out[bo + j] = skel[j + selpad];
        __syncthreads();   // skel/swords reuse next iteration
    }
}

extern "C" void kernel_launch(void* const* d_in, const int* in_sizes, int n_in,
                              void* d_out, int out_size, void* d_ws, size_t ws_size,
                              hipStream_t stream) {
    const float* score = (const float*)d_in[0];
    const int* row_splits = (const int*)d_in[1];
    int n = in_sizes[0];
    int n_seg = in_sizes[1] - 1;
    int M = out_size - (n_seg + 1) - n;
    int nb = (n + TILE - 1) / TILE;
    int nwords = (n + 63) / 64;
    int nchunk = (nb + CHUNK - 1) / CHUNK;

    u64* seg_packed   = (u64*)d_ws;                              // MAXSEG*SEGSTRIDE u64 (0xFF)
    int* chunk_sums   = (int*)(seg_packed + MAXSEG * SEGSTRIDE); // NCMAX*CHSTRIDE int (0xFF = -1)
    int* ctr          = chunk_sums + NCMAX * CHSTRIDE;           // 32 int (0xFF = -1)
    uintptr_t pv_addr = (uintptr_t)(ctr + 32);
    pv_addr = (pv_addr + 7) & ~(uintptr_t)7;
    u64* partial_val  = (u64*)pv_addr;                           // 2*nb u64
    int* partial_seg  = (int*)(partial_val + 2 * nb);            // 2*nb int
    int* block_counts = partial_seg + 2 * nb;                    // nb int
    uintptr_t bm_addr = (uintptr_t)(block_counts + nb);
    bm_addr = (bm_addr + 7) & ~(uintptr_t)7;
    u64* bitmask      = (u64*)bm_addr;                           // nwords u64

    int* out = (int*)d_out;
    int* sel_out   = out;
    int* newrs_out = out + M;
    int* back_out  = out + M + (n_seg + 1);

    // grid sized for GUARANTEED co-residency (spin barrier cannot deadlock):
    // blocks/CU from the occupancy query for this exact kernel, capped at 8.
    static int gsize = 0;
    if (gsize == 0) {
        int mb = 0;
        if (hipOccupancyMaxActiveBlocksPerMultiprocessor(&mb, k_fused, BLOCK, 0) != hipSuccess
            || mb < 1) mb = 1;
        if (mb > 8) mb = 8;
        gsize = 256 * mb;
    }
    int G = gsize;

    // one tiny memset (~25KB): seg_packed=~0 (atomicMin identity),
    // chunk_sums=-1 (-1-encoded), ctr=-1 (cumulative barrier counter)
    size_t init_bytes = (size_t)((char*)(ctr + 32) - (char*)d_ws);
    hipMemsetAsync(d_ws, 0xFF, init_bytes, stream);
    hipLaunchKernelGGL(k_fused, dim3(G), dim3(BLOCK), 0, stream,
                       score, row_splits, n_seg, n, nb, nwords, nchunk, M, G,
                       partial_val, partial_seg, bitmask, block_counts,
                       seg_packed, chunk_sums, ctr,
                       sel_out, back_out, newrs_out);
}

// Round 7
// 229.679 us; speedup vs baseline: 1.0184x; 1.0184x over previous
//
#include <hip/hip_runtime.h>
#include <stdint.h>

#define BLOCK 256
#define ITEMS 8
#define TILE (BLOCK * ITEMS)   // 2048 elements per block
#define WPB (TILE / 64)        // 32 bitmask words per block
#define MAXSEG 64
#define THRESH 0.1f

typedef unsigned long long u64;

__device__ __forceinline__ int find_seg(const int* rs, int n_seg, int i) {
    // largest s with rs[s] <= i
    int lo = 0, hi = n_seg;
    while (hi - lo > 1) {
        int mid = (lo + hi) >> 1;
        if (rs[mid] <= i) lo = mid; else hi = mid;
    }
    return lo;
}

// Pass 1 (R0 body + eq-count): single read of score producing
//   - threshold keep-bitmask (s > THRESH); min-tie bits are NEVER set globally
//     (k_output fixes its own tile locally in LDS)
//   - per-block threshold keep counts
//   - per-portion packed (min_bits<<32 | idx) partials (<=2 segments/block)
//   - per-portion COUNT of elements equal to the portion min (partial_cnt),
//     carried through the reductions as (min, count) pairs. This is what lets
//     k_scanq correct counts analytically and k_segfix be deleted.
// No atomics, no fences, no workspace init (R1/R3/R6 lessons).
__global__ __launch_bounds__(BLOCK) void k_pass1(const float* __restrict__ score,
        const int* __restrict__ row_splits, int n_seg, int n, int nwords,
        u64* __restrict__ partial_val, int* __restrict__ partial_seg,
        int* __restrict__ partial_cnt,
        u64* __restrict__ bitmask, int* __restrict__ block_counts) {
    __shared__ int rs[MAXSEG + 1];
    __shared__ u64 wval[8];
    __shared__ int wcnt[8];
    __shared__ int wseg[8];
    __shared__ int wsum[4];
    for (int j = threadIdx.x; j <= n_seg; j += BLOCK) rs[j] = row_splits[j];
    __syncthreads();
    int lane = threadIdx.x & 63, wv = threadIdx.x >> 6;
    int wbase = blockIdx.x * TILE + wv * 512;
    u64 m0 = ~0ull, m1 = ~0ull;
    int c0 = 0, c1 = 0;
    int sf = -1, sl = -1, cnt = 0;
    if (wbase < n) {   // wave-uniform
        int wend = min(n, wbase + 512) - 1;
        sf = find_seg(rs, n_seg, wbase);
        sl = find_seg(rs, n_seg, wend);
        int bval = (sl != sf) ? rs[sf + 1] : 0x7FFFFFFF;
        int tbase = wbase + lane * 8;
        unsigned int kbyte = 0;
        if (tbase < n) {
            float v[8];
            if (tbase + 8 <= n) {
                float4 f0 = *(const float4*)(score + tbase);
                float4 f1 = *(const float4*)(score + tbase + 4);
                v[0]=f0.x; v[1]=f0.y; v[2]=f0.z; v[3]=f0.w;
                v[4]=f1.x; v[5]=f1.y; v[6]=f1.z; v[7]=f1.w;
            } else {
                for (int j = 0; j < 8; j++) v[j] = (tbase + j < n) ? score[tbase + j] : 1.0f;
            }
            #pragma unroll
            for (int j = 0; j < 8; j++) {
                int i = tbase + j;
                if (i < n) {
                    unsigned int sb = __float_as_uint(v[j]);
                    u64 p = ((u64)sb << 32) | (unsigned int)i;
                    if (i < bval) {
                        unsigned int a = (unsigned int)(m0 >> 32);
                        if (sb < a) { m0 = p; c0 = 1; }
                        else if (sb == a) c0++;        // m0 keeps smallest idx (i ascending)
                    } else {
                        unsigned int a = (unsigned int)(m1 >> 32);
                        if (sb < a) { m1 = p; c1 = 1; }
                        else if (sb == a) c1++;
                    }
                    if (v[j] > THRESH) kbyte |= 1u << j;
                }
            }
            cnt = __popc(kbyte);
        }
        // assemble 64-bit words within groups of 8 lanes
        u64 acc = ((u64)kbyte) << (8 * (lane & 7));
        acc |= __shfl_xor((unsigned long long)acc, 1, 64);
        acc |= __shfl_xor((unsigned long long)acc, 2, 64);
        acc |= __shfl_xor((unsigned long long)acc, 4, 64);
        int src = (lane < 8) ? (8 * lane) : lane;
        u64 myword = __shfl((unsigned long long)acc, src, 64);
        for (int o = 32; o > 0; o >>= 1) {
            u64 om = __shfl_down((unsigned long long)m0, o, 64);
            int oc = __shfl_down(c0, o, 64);
            unsigned int a = (unsigned int)(m0 >> 32), bb = (unsigned int)(om >> 32);
            if (bb < a) { m0 = om; c0 = oc; }
            else if (bb == a) { c0 += oc; if (om < m0) m0 = om; }
            om = __shfl_down((unsigned long long)m1, o, 64);
            oc = __shfl_down(c1, o, 64);
            a = (unsigned int)(m1 >> 32); bb = (unsigned int)(om >> 32);
            if (bb < a) { m1 = om; c1 = oc; }
            else if (bb == a) { c1 += oc; if (om < m1) m1 = om; }
            cnt += __shfl_down(cnt, o, 64);
        }
        if (lane < 8) {
            int w = (wbase >> 6) + lane;
            if (w < nwords) bitmask[w] = myword;
        }
    }
    if (lane == 0) {
        wval[2 * wv] = m0;     wcnt[2 * wv] = c0;     wseg[2 * wv] = sf;
        wval[2 * wv + 1] = m1; wcnt[2 * wv + 1] = c1; wseg[2 * wv + 1] = (sl != sf) ? sl : -1;
        wsum[wv] = (wbase < n) ? cnt : 0;
    }
    __syncthreads();
    if (threadIdx.x == 0) {
        int base = blockIdx.x * TILE;
        int endi = min(n, base + TILE) - 1;
        int s0 = find_seg(rs, n_seg, base);
        int s1 = find_seg(rs, n_seg, endi);
        u64 o0 = ~0ull, o1 = ~0ull;
        int f0 = 0, f1 = 0;
        for (int k = 0; k < 8; k++) {
            if (wseg[k] == s0) {
                u64 om = wval[k]; int oc = wcnt[k];
                unsigned int a = (unsigned int)(o0 >> 32), bb = (unsigned int)(om >> 32);
                if (bb < a) { o0 = om; f0 = oc; }
                else if (bb == a) { f0 += oc; if (om < o0) o0 = om; }
            } else if (wseg[k] == s1) {
                u64 om = wval[k]; int oc = wcnt[k];
                unsigned int a = (unsigned int)(o1 >> 32), bb = (unsigned int)(om >> 32);
                if (bb < a) { o1 = om; f1 = oc; }
                else if (bb == a) { f1 += oc; if (om < o1) o1 = om; }
            }
        }
        partial_val[2 * blockIdx.x] = o0;
        partial_seg[2 * blockIdx.x] = s0;
        partial_cnt[2 * blockIdx.x] = f0;
        partial_val[2 * blockIdx.x + 1] = o1;
        partial_seg[2 * blockIdx.x + 1] = (s1 != s0) ? s1 : -1;
        partial_cnt[2 * blockIdx.x + 1] = f1;
        block_counts[blockIdx.x] = wsum[0] + wsum[1] + wsum[2] + wsum[3];
    }
}

// Correction for portion e: +partial_cnt[e] iff the portion's min equals its
// segment's min and segmin <= THRESH (those elements are kept but have no
// threshold bit). segmin comes from LDS.
__device__ __forceinline__ int corr_e(int e, const int* __restrict__ ps,
        const u64* __restrict__ pv, const int* __restrict__ pc,
        const u64* segmin) {
    int s = ps[e];
    if (s < 0) return 0;
    unsigned int smb = (unsigned int)(segmin[s] >> 32);
    if (__uint_as_float(smb) > THRESH) return 0;
    if ((unsigned int)(pv[e] >> 32) != smb) return 0;
    return pc[e];
}

// Pass 2 (single tiny block; replaces segfix+scanq): reduce seg mins from
// partials (filtered LDS atomicMin), publish seg_packed; exclusive-scan
// CORRECTED block counts (threshold count + analytic min-tie corrections) ->
// block_offsets; then per-thread queries (newrs + rep_pos) over the pure
// threshold bitmask + corrections. Rep needs no own-portion correction (it is
// by packed-min construction the first min element of its segment); only a
// preceding-portion (previous segment) correction applies.
__global__ __launch_bounds__(BLOCK) void k_scanq(const int* __restrict__ counts,
        int* __restrict__ offsets, int nb,
        const int* __restrict__ row_splits, int n_seg, int n, int M,
        const u64* __restrict__ partial_val, const int* __restrict__ partial_seg,
        const int* __restrict__ partial_cnt,
        u64* __restrict__ seg_packed, const u64* __restrict__ bitmask,
        int* __restrict__ rep_pos, int* __restrict__ newrs_out) {
    __shared__ u64 segmin[MAXSEG];
    __shared__ int wtot[BLOCK / 64];
    int tid = threadIdx.x, lane = tid & 63, wv = tid >> 6;
    if (tid < MAXSEG) segmin[tid] = ~0ull;
    __syncthreads();
    int ne = 2 * nb;
    for (int e = tid; e < ne; e += BLOCK) {
        int s = partial_seg[e];
        if (s >= 0) {
            u64 pv = partial_val[e];
            if (pv < segmin[s]) atomicMin(&segmin[s], pv);   // filtered: few real atomics
        }
    }
    __syncthreads();
    if (tid < n_seg) seg_packed[tid] = segmin[tid];
    {
        int per = (nb + BLOCK - 1) / BLOCK;
        int s = per * tid, e = min(nb, s + per);
        int sum = 0;
        for (int i = s; i < e; i++)
            sum += counts[i] + corr_e(2 * i, partial_seg, partial_val, partial_cnt, segmin)
                             + corr_e(2 * i + 1, partial_seg, partial_val, partial_cnt, segmin);
        int incl = sum;
        for (int o = 1; o < 64; o <<= 1) {
            int t = __shfl_up(incl, o, 64);
            if (lane >= o) incl += t;
        }
        if (lane == 63) wtot[wv] = incl;
        __syncthreads();
        int excl = incl - sum;
        for (int k = 0; k < wv; k++) excl += wtot[k];
        for (int i = s; i < e; i++) {
            offsets[i] = excl;
            excl += counts[i] + corr_e(2 * i, partial_seg, partial_val, partial_cnt, segmin)
                              + corr_e(2 * i + 1, partial_seg, partial_val, partial_cnt, segmin);
        }
    }
    __syncthreads();
    int nq = 2 * n_seg + 1;
    if (tid < nq) {
        int qseg = (tid <= n_seg) ? tid : (tid - (n_seg + 1));
        unsigned int uidx;
        if (tid <= n_seg) uidx = (unsigned int)row_splits[tid];
        else uidx = (unsigned int)(segmin[qseg] & 0xFFFFFFFFu);
        int result;
        if (uidx >= (unsigned int)n) {
            result = M;
        } else {
            int idx = (int)uidx;
            int T = idx / TILE;
            int wq = idx >> 6;
            int cnt = offsets[T];
            for (int w = T * WPB; w < wq; w++) cnt += __popcll(bitmask[w]);
            if (idx & 63) cnt += __popcll(bitmask[wq] & ((1ull << (idx & 63)) - 1));
            // preceding portion of this tile belongs to an earlier segment ->
            // its min-tied elements all precede uidx
            if (partial_seg[2 * T] != qseg)
                cnt += corr_e(2 * T, partial_seg, partial_val, partial_cnt, segmin);
            result = cnt;
        }
        if (tid <= n_seg) newrs_out[tid] = result;
        else rep_pos[qseg] = result;
    }
}

// Pass 3 (R0 body + local min-tie fix): stage own tile's threshold bitmask
// words into LDS; if a portion's min matches its segmin<=THRESH (rare: ~64
// tiles device-wide), re-read ONLY that portion's scores and set the min-tie
// bits in LDS (32-bit LDS atomicOr). wpre/tot then reflect corrected bits,
// consistent with scanq's corrected offsets. Everything downstream is the
// proven R0 output body: back values in registers for 4 phase-aligned
// positions -> dwordx4 stores; sel indices staged in LDS with slot offset so
// vector reads are aligned ds_read_b128. Assumes <=1 segment boundary per
// 2048-elem block (seg len >> 2048 here).
__global__ __launch_bounds__(BLOCK) void k_output(const float* __restrict__ score,
        const int* __restrict__ row_splits, int n_seg, int n,
        const u64* __restrict__ partial_val, const int* __restrict__ partial_seg,
        const u64* __restrict__ seg_packed,
        const int* __restrict__ rep_pos, const u64* __restrict__ bitmask,
        const int* __restrict__ block_offsets,
        int* __restrict__ sel_out, int* __restrict__ back_out) {
    __shared__ int rs[MAXSEG + 1];
    __shared__ u64 swords[WPB];
    __shared__ int wpre[WPB];
    __shared__ int shead[4];   // bval, rep0, rep1, tot
    __shared__ int fix_n;
    __shared__ int fix_lo[2], fix_hi[2];
    __shared__ unsigned int fix_smb[2];
    __shared__ alignas(16) int skel[TILE + 8];
    for (int j = threadIdx.x; j <= n_seg; j += BLOCK) rs[j] = row_splits[j];
    int base = blockIdx.x * TILE;
    int lim = min(TILE, n - base);
    int nw = (lim + 63) >> 6;
    for (int j = threadIdx.x; j < nw; j += BLOCK) swords[j] = bitmask[(base >> 6) + j];
    __syncthreads();
    if (threadIdx.x == 0) {
        int b = blockIdx.x;
        int s0 = find_seg(rs, n_seg, base);
        int s1 = find_seg(rs, n_seg, base + lim - 1);
        int bval = (s1 != s0) ? rs[s0 + 1] : 0x7FFFFFFF;
        shead[0] = bval;
        shead[1] = rep_pos[s0];
        shead[2] = rep_pos[s1];
        int nf = 0;
        #pragma unroll
        for (int h = 0; h < 2; h++) {
            int e = 2 * b + h;
            int s = partial_seg[e];
            if (s >= 0) {
                unsigned int smb = (unsigned int)(seg_packed[s] >> 32);
                if (__uint_as_float(smb) <= THRESH &&
                    (unsigned int)(partial_val[e] >> 32) == smb) {
                    fix_lo[nf] = h ? bval : base;
                    fix_hi[nf] = h ? (base + lim) : min(bval, base + lim);
                    fix_smb[nf] = smb;
                    nf++;
                }
            }
        }
        fix_n = nf;
    }
    __syncthreads();
    for (int k = 0; k < fix_n; k++) {        // fix_n block-uniform; usually 0
        unsigned int smb = fix_smb[k];
        for (int i = fix_lo[k] + threadIdx.x; i < fix_hi[k]; i += BLOCK) {
            if (__float_as_uint(score[i]) == smb) {
                int j = i - base;
                atomicOr(&((unsigned int*)swords)[j >> 5], 1u << (j & 31));
            }
        }
    }
    __syncthreads();
    if (threadIdx.x == 0) {
        int acc = 0;
        for (int k = 0; k < nw; k++) { wpre[k] = acc; acc += __popcll(swords[k]); }
        shead[3] = acc;
    }
    __syncthreads();
    int bval = shead[0], rep0 = shead[1], rep1 = shead[2], tot = shead[3];
    int bo = block_offsets[blockIdx.x];
    // phases
    int st_b = (int)((4 - ((((uintptr_t)(back_out + base)) >> 2) & 3)) & 3);
    if (st_b > lim) st_b = lim;
    int st_s = (int)((4 - ((((uintptr_t)(sel_out + bo)) >> 2) & 3)) & 3);
    if (st_s > tot) st_s = tot;
    int selpad = 4 - st_s;          // skel slot = (pos - bo) + selpad; first aligned slot = 4

    // main: full int4 groups of back_out; also stage kept indices into skel
    int ngroups = (lim - st_b) >> 2;
    for (int g = threadIdx.x; g < ngroups; g += BLOCK) {
        int j0 = st_b + 4 * g;
        int vals[4];
        #pragma unroll
        for (int k = 0; k < 4; k++) {
            int j = j0 + k;
            int widx = j >> 6, r = j & 63;
            u64 w = swords[widx];
            int i = base + j;
            if ((w >> r) & 1) {
                int pos = bo + wpre[widx] + __popcll(w & ((1ull << r) - 1));
                vals[k] = pos;
                skel[pos - bo + selpad] = i;
            } else {
                vals[k] = (i >= bval) ? rep1 : rep0;
            }
        }
        *(int4*)(back_out + base + j0) = make_int4(vals[0], vals[1], vals[2], vals[3]);
    }
    // edges of back region (<=3 head, <=3 tail)
    for (int j = threadIdx.x; j < st_b; j += BLOCK) {
        int widx = j >> 6, r = j & 63;
        u64 w = swords[widx];
        int i = base + j, val;
        if ((w >> r) & 1) {
            int pos = bo + wpre[widx] + __popcll(w & ((1ull << r) - 1));
            val = pos;
            skel[pos - bo + selpad] = i;
        } else val = (i >= bval) ? rep1 : rep0;
        back_out[i] = val;
    }
    for (int j = st_b + 4 * ngroups + threadIdx.x; j < lim; j += BLOCK) {
        int widx = j >> 6, r = j & 63;
        u64 w = swords[widx];
        int i = base + j, val;
        if ((w >> r) & 1) {
            int pos = bo + wpre[widx] + __popcll(w & ((1ull << r) - 1));
            val = pos;
            skel[pos - bo + selpad] = i;
        } else val = (i >= bval) ? rep1 : rep0;
        back_out[i] = val;
    }
    __syncthreads();
    // sel_out: aligned int4 stores fed by aligned ds_read_b128
    int nvg = (tot - st_s) >> 2;
    for (int g = threadIdx.x; g < nvg; g += BLOCK) {
        int4 v = *(const int4*)&skel[4 + 4 * g];
        *(int4*)(sel_out + bo + st_s + 4 * g) = v;
    }
    for (int j = threadIdx.x; j < st_s; j += BLOCK) sel_out[bo + j] = skel[j + selpad];
    for (int j = st_s + 4 * nvg + threadIdx.x; j < tot; j += BLOCK) sel_out[bo + j] = skel[j + selpad];
}

extern "C" void kernel_launch(void* const* d_in, const int* in_sizes, int n_in,
                              void* d_out, int out_size, void* d_ws, size_t ws_size,
                              hipStream_t stream) {
    const float* score = (const float*)d_in[0];
    const int* row_splits = (const int*)d_in[1];
    int n = in_sizes[0];
    int n_seg = in_sizes[1] - 1;
    int M = out_size - (n_seg + 1) - n;
    int nb = (n + TILE - 1) / TILE;
    int nwords = (n + 63) / 64;

    u64* seg_packed   = (u64*)d_ws;                      // MAXSEG u64 (written by k_scanq)
    u64* partial_val  = seg_packed + MAXSEG;             // 2*nb u64
    int* partial_seg  = (int*)(partial_val + 2 * nb);    // 2*nb int
    int* partial_cnt  = partial_seg + 2 * nb;            // 2*nb int
    int* block_counts = partial_cnt + 2 * nb;            // nb int
    int* block_offsets= block_counts + nb;               // nb int
    int* rep_pos      = block_offsets + nb;              // 64 int
    uintptr_t bm_addr = (uintptr_t)(rep_pos + MAXSEG);
    bm_addr = (bm_addr + 7) & ~(uintptr_t)7;
    u64* bitmask      = (u64*)bm_addr;                   // nwords u64

    int* out = (int*)d_out;
    int* sel_out   = out;
    int* newrs_out = out + M;
    int* back_out  = out + M + (n_seg + 1);

    // 3 dispatches, zero workspace init, zero global atomics
    hipLaunchKernelGGL(k_pass1, dim3(nb), dim3(BLOCK), 0, stream,
                       score, row_splits, n_seg, n, nwords,
                       partial_val, partial_seg, partial_cnt, bitmask, block_counts);
    hipLaunchKernelGGL(k_scanq, dim3(1), dim3(BLOCK), 0, stream,
                       block_counts, block_offsets, nb,
                       row_splits, n_seg, n, M,
                       partial_val, partial_seg, partial_cnt,
                       seg_packed, bitmask, rep_pos, newrs_out);
    hipLaunchKernelGGL(k_output, dim3(nb), dim3(BLOCK), 0, stream,
                       score, row_splits, n_seg, n,
                       partial_val, partial_seg, seg_packed,
                       rep_pos, bitmask, block_offsets,
                       sel_out, back_out);
}

// Round 8
// 194.283 us; speedup vs baseline: 1.2039x; 1.1822x over previous
//
#include <hip/hip_runtime.h>
#include <stdint.h>

#define BLOCK 256
#define ITEMS 8
#define TILE (BLOCK * ITEMS)   // 2048 elements per block
#define WPB (TILE / 64)        // 32 bitmask words per block
#define MAXSEG 64
#define BT 1024                // k_scanq block size (16 waves: latency hiding)
#define THRESH 0.1f

typedef unsigned long long u64;

__device__ __forceinline__ int find_seg(const int* rs, int n_seg, int i) {
    // largest s with rs[s] <= i
    int lo = 0, hi = n_seg;
    while (hi - lo > 1) {
        int mid = (lo + hi) >> 1;
        if (rs[mid] <= i) lo = mid; else hi = mid;
    }
    return lo;
}

// Portion record, ONE 16B load: x=seg, y=eq-count, z=val_lo(idx), w=val_hi(score bits)
// Packing (R7 lesson): k_scanq's corr logic had branch-guarded loads across 3
// arrays -> serialized L2 round-trips -> 76us single-block kernel at 0.013%
// VALUBusy. One unconditional dwordx4 makes every iteration's load hoistable.
__device__ __forceinline__ u64 pval(int4 p) {
    return ((u64)(unsigned int)p.w << 32) | (unsigned int)p.z;
}

// correction for a portion: +count iff portion min == its segment min <= THRESH
// (those elements are kept but carry no threshold bit). All inputs in registers
// or LDS after the single pack load.
__device__ __forceinline__ int corr_p(int4 p, const u64* segmin) {
    if (p.x < 0) return 0;
    unsigned int smb = (unsigned int)(segmin[p.x] >> 32);
    return (__uint_as_float(smb) <= THRESH && (unsigned int)p.w == smb) ? p.y : 0;
}

// Pass 1 (R0 body + eq-count pairs): single read of score producing
//   - threshold keep-bitmask (s > THRESH); min-tie bits are NEVER set globally
//     (k_output fixes its own tile locally in LDS)
//   - per-block threshold keep counts
//   - per-portion packed int4 record (seg, eq-count, min idx, min bits)
// No atomics, no fences, no workspace init (R1/R3/R6 lessons).
__global__ __launch_bounds__(BLOCK) void k_pass1(const float* __restrict__ score,
        const int* __restrict__ row_splits, int n_seg, int n, int nwords,
        int4* __restrict__ partial_pack,
        u64* __restrict__ bitmask, int* __restrict__ block_counts) {
    __shared__ int rs[MAXSEG + 1];
    __shared__ u64 wval[8];
    __shared__ int wcnt[8];
    __shared__ int wseg[8];
    __shared__ int wsum[4];
    for (int j = threadIdx.x; j <= n_seg; j += BLOCK) rs[j] = row_splits[j];
    __syncthreads();
    int lane = threadIdx.x & 63, wv = threadIdx.x >> 6;
    int wbase = blockIdx.x * TILE + wv * 512;
    u64 m0 = ~0ull, m1 = ~0ull;
    int c0 = 0, c1 = 0;
    int sf = -1, sl = -1, cnt = 0;
    if (wbase < n) {   // wave-uniform
        int wend = min(n, wbase + 512) - 1;
        sf = find_seg(rs, n_seg, wbase);
        sl = find_seg(rs, n_seg, wend);
        int bval = (sl != sf) ? rs[sf + 1] : 0x7FFFFFFF;
        int tbase = wbase + lane * 8;
        unsigned int kbyte = 0;
        if (tbase < n) {
            float v[8];
            if (tbase + 8 <= n) {
                float4 f0 = *(const float4*)(score + tbase);
                float4 f1 = *(const float4*)(score + tbase + 4);
                v[0]=f0.x; v[1]=f0.y; v[2]=f0.z; v[3]=f0.w;
                v[4]=f1.x; v[5]=f1.y; v[6]=f1.z; v[7]=f1.w;
            } else {
                for (int j = 0; j < 8; j++) v[j] = (tbase + j < n) ? score[tbase + j] : 1.0f;
            }
            #pragma unroll
            for (int j = 0; j < 8; j++) {
                int i = tbase + j;
                if (i < n) {
                    unsigned int sb = __float_as_uint(v[j]);
                    u64 p = ((u64)sb << 32) | (unsigned int)i;
                    if (i < bval) {
                        unsigned int a = (unsigned int)(m0 >> 32);
                        if (sb < a) { m0 = p; c0 = 1; }
                        else if (sb == a) c0++;        // m0 keeps smallest idx (i ascending)
                    } else {
                        unsigned int a = (unsigned int)(m1 >> 32);
                        if (sb < a) { m1 = p; c1 = 1; }
                        else if (sb == a) c1++;
                    }
                    if (v[j] > THRESH) kbyte |= 1u << j;
                }
            }
            cnt = __popc(kbyte);
        }
        // assemble 64-bit words within groups of 8 lanes
        u64 acc = ((u64)kbyte) << (8 * (lane & 7));
        acc |= __shfl_xor((unsigned long long)acc, 1, 64);
        acc |= __shfl_xor((unsigned long long)acc, 2, 64);
        acc |= __shfl_xor((unsigned long long)acc, 4, 64);
        int src = (lane < 8) ? (8 * lane) : lane;
        u64 myword = __shfl((unsigned long long)acc, src, 64);
        for (int o = 32; o > 0; o >>= 1) {
            u64 om = __shfl_down((unsigned long long)m0, o, 64);
            int oc = __shfl_down(c0, o, 64);
            unsigned int a = (unsigned int)(m0 >> 32), bb = (unsigned int)(om >> 32);
            if (bb < a) { m0 = om; c0 = oc; }
            else if (bb == a) { c0 += oc; if (om < m0) m0 = om; }
            om = __shfl_down((unsigned long long)m1, o, 64);
            oc = __shfl_down(c1, o, 64);
            a = (unsigned int)(m1 >> 32); bb = (unsigned int)(om >> 32);
            if (bb < a) { m1 = om; c1 = oc; }
            else if (bb == a) { c1 += oc; if (om < m1) m1 = om; }
            cnt += __shfl_down(cnt, o, 64);
        }
        if (lane < 8) {
            int w = (wbase >> 6) + lane;
            if (w < nwords) bitmask[w] = myword;
        }
    }
    if (lane == 0) {
        wval[2 * wv] = m0;     wcnt[2 * wv] = c0;     wseg[2 * wv] = sf;
        wval[2 * wv + 1] = m1; wcnt[2 * wv + 1] = c1; wseg[2 * wv + 1] = (sl != sf) ? sl : -1;
        wsum[wv] = (wbase < n) ? cnt : 0;
    }
    __syncthreads();
    if (threadIdx.x == 0) {
        int base = blockIdx.x * TILE;
        int endi = min(n, base + TILE) - 1;
        int s0 = find_seg(rs, n_seg, base);
        int s1 = find_seg(rs, n_seg, endi);
        u64 o0 = ~0ull, o1 = ~0ull;
        int f0 = 0, f1 = 0;
        for (int k = 0; k < 8; k++) {
            if (wseg[k] == s0) {
                u64 om = wval[k]; int oc = wcnt[k];
                unsigned int a = (unsigned int)(o0 >> 32), bb = (unsigned int)(om >> 32);
                if (bb < a) { o0 = om; f0 = oc; }
                else if (bb == a) { f0 += oc; if (om < o0) o0 = om; }
            } else if (wseg[k] == s1) {
                u64 om = wval[k]; int oc = wcnt[k];
                unsigned int a = (unsigned int)(o1 >> 32), bb = (unsigned int)(om >> 32);
                if (bb < a) { o1 = om; f1 = oc; }
                else if (bb == a) { f1 += oc; if (om < o1) o1 = om; }
            }
        }
        partial_pack[2 * blockIdx.x] =
            make_int4(s0, f0, (int)(o0 & 0xFFFFFFFFu), (int)(o0 >> 32));
        partial_pack[2 * blockIdx.x + 1] =
            make_int4((s1 != s0) ? s1 : -1, f1, (int)(o1 & 0xFFFFFFFFu), (int)(o1 >> 32));
        block_counts[blockIdx.x] = wsum[0] + wsum[1] + wsum[2] + wsum[3];
    }
}

// Pass 2 (single block, BT=1024 threads): reduce seg mins from packs (filtered
// LDS atomicMin), publish seg_packed; exclusive-scan CORRECTED block counts
// (threshold count + analytic min-tie corrections) -> block_offsets; then
// per-thread queries (newrs + rep_pos). Every global iteration issues exactly
// one unconditional 16B pack load (+4B count) -> fully pipelined; the R7
// version's branch-guarded 3-array loads serialized to 76us.
__global__ __launch_bounds__(BT) void k_scanq(const int* __restrict__ counts,
        int* __restrict__ offsets, int nb,
        const int* __restrict__ row_splits, int n_seg, int n, int M,
        const int4* __restrict__ pack,
        u64* __restrict__ seg_packed, const u64* __restrict__ bitmask,
        int* __restrict__ rep_pos, int* __restrict__ newrs_out) {
    __shared__ u64 segmin[MAXSEG];
    __shared__ int wtot[BT / 64];
    int tid = threadIdx.x, lane = tid & 63, wv = tid >> 6;
    if (tid < MAXSEG) segmin[tid] = ~0ull;
    __syncthreads();
    int ne = 2 * nb;
    for (int e = tid; e < ne; e += BT) {
        int4 p = pack[e];                    // unconditional, pipelined
        if (p.x >= 0) {
            u64 v = pval(p);
            if (v < segmin[p.x])
                atomicMin((unsigned long long*)&segmin[p.x], v);  // filtered, rare
        }
    }
    __syncthreads();
    if (tid < n_seg) seg_packed[tid] = segmin[tid];
    {
        int per = (nb + BT - 1) / BT;        // 7 at nb=6250
        int s = per * tid, e = min(nb, s + per);
        int sum = 0;
        for (int i = s; i < e; i++) {
            int4 a = pack[2 * i], b = pack[2 * i + 1];   // unconditional
            sum += counts[i] + corr_p(a, segmin) + corr_p(b, segmin);
        }
        int incl = sum;
        for (int o = 1; o < 64; o <<= 1) {
            int t = __shfl_up(incl, o, 64);
            if (lane >= o) incl += t;
        }
        if (lane == 63) wtot[wv] = incl;
        __syncthreads();
        int excl = incl - sum;
        for (int k = 0; k < wv; k++) excl += wtot[k];
        for (int i = s; i < e; i++) {        // recompute from L1-hot lines
            int4 a = pack[2 * i], b = pack[2 * i + 1];
            offsets[i] = excl;
            excl += counts[i] + corr_p(a, segmin) + corr_p(b, segmin);
        }
    }
    __syncthreads();
    int nq = 2 * n_seg + 1;
    if (tid < nq) {
        int qseg = (tid <= n_seg) ? tid : (tid - (n_seg + 1));
        unsigned int uidx;
        if (tid <= n_seg) uidx = (unsigned int)row_splits[tid];
        else uidx = (unsigned int)(segmin[qseg] & 0xFFFFFFFFu);
        int result;
        if (uidx >= (unsigned int)n) {
            result = M;
        } else {
            int idx = (int)uidx;
            int T = idx / TILE;
            int wq = idx >> 6;
            int cnt = offsets[T];
            for (int w = T * WPB; w < wq; w++) cnt += __popcll(bitmask[w]);
            if (idx & 63) cnt += __popcll(bitmask[wq] & ((1ull << (idx & 63)) - 1));
            // preceding portion of this tile belongs to an earlier segment ->
            // its min-tied elements all precede uidx. (The query element itself
            // is the FIRST min of its own segment, so no own-portion corr.)
            int4 a = pack[2 * T];
            if (a.x != qseg) cnt += corr_p(a, segmin);
            result = cnt;
        }
        if (tid <= n_seg) newrs_out[tid] = result;
        else rep_pos[qseg] = result;
    }
}

// Pass 3 (R0 body + local min-tie fix): stage own tile's threshold bitmask
// words into LDS; if a portion's min matches its segmin<=THRESH (rare: ~64
// tiles device-wide), re-read ONLY that portion's scores and set the min-tie
// bits in LDS (32-bit LDS atomicOr). wpre/tot then reflect corrected bits,
// consistent with scanq's corrected offsets. Everything downstream is the
// proven R0 output body. Assumes <=1 segment boundary per 2048-elem block.
__global__ __launch_bounds__(BLOCK) void k_output(const float* __restrict__ score,
        const int* __restrict__ row_splits, int n_seg, int n,
        const int4* __restrict__ pack, const u64* __restrict__ seg_packed,
        const int* __restrict__ rep_pos, const u64* __restrict__ bitmask,
        const int* __restrict__ block_offsets,
        int* __restrict__ sel_out, int* __restrict__ back_out) {
    __shared__ int rs[MAXSEG + 1];
    __shared__ u64 swords[WPB];
    __shared__ int wpre[WPB];
    __shared__ int shead[4];   // bval, rep0, rep1, tot
    __shared__ int fix_n;
    __shared__ int fix_lo[2], fix_hi[2];
    __shared__ unsigned int fix_smb[2];
    __shared__ alignas(16) int skel[TILE + 8];
    for (int j = threadIdx.x; j <= n_seg; j += BLOCK) rs[j] = row_splits[j];
    int base = blockIdx.x * TILE;
    int lim = min(TILE, n - base);
    int nw = (lim + 63) >> 6;
    for (int j = threadIdx.x; j < nw; j += BLOCK) swords[j] = bitmask[(base >> 6) + j];
    __syncthreads();
    if (threadIdx.x == 0) {
        int b = blockIdx.x;
        int s0 = find_seg(rs, n_seg, base);
        int s1 = find_seg(rs, n_seg, base + lim - 1);
        int bval = (s1 != s0) ? rs[s0 + 1] : 0x7FFFFFFF;
        shead[0] = bval;
        shead[1] = rep_pos[s0];
        shead[2] = rep_pos[s1];
        int nf = 0;
        int4 pa = pack[2 * b], pb = pack[2 * b + 1];   // both issued up front
        #pragma unroll
        for (int h = 0; h < 2; h++) {
            int4 p = h ? pb : pa;
            if (p.x >= 0) {
                unsigned int smb = (unsigned int)(seg_packed[p.x] >> 32);
                if (__uint_as_float(smb) <= THRESH && (unsigned int)p.w == smb) {
                    fix_lo[nf] = h ? bval : base;
                    fix_hi[nf] = h ? (base + lim) : min(bval, base + lim);
                    fix_smb[nf] = smb;
                    nf++;
                }
            }
        }
        fix_n = nf;
    }
    __syncthreads();
    for (int k = 0; k < fix_n; k++) {        // fix_n block-uniform; usually 0
        unsigned int smb = fix_smb[k];
        for (int i = fix_lo[k] + threadIdx.x; i < fix_hi[k]; i += BLOCK) {
            if (__float_as_uint(score[i]) == smb) {
                int j = i - base;
                atomicOr(&((unsigned int*)swords)[j >> 5], 1u << (j & 31));
            }
        }
    }
    __syncthreads();
    if (threadIdx.x == 0) {
        int acc = 0;
        for (int k = 0; k < nw; k++) { wpre[k] = acc; acc += __popcll(swords[k]); }
        shead[3] = acc;
    }
    __syncthreads();
    int bval = shead[0], rep0 = shead[1], rep1 = shead[2], tot = shead[3];
    int bo = block_offsets[blockIdx.x];
    // phases
    int st_b = (int)((4 - ((((uintptr_t)(back_out + base)) >> 2) & 3)) & 3);
    if (st_b > lim) st_b = lim;
    int st_s = (int)((4 - ((((uintptr_t)(sel_out + bo)) >> 2) & 3)) & 3);
    if (st_s > tot) st_s = tot;
    int selpad = 4 - st_s;          // skel slot = (pos - bo) + selpad; first aligned slot = 4

    // main: full int4 groups of back_out; also stage kept indices into skel
    int ngroups = (lim - st_b) >> 2;
    for (int g = threadIdx.x; g < ngroups; g += BLOCK) {
        int j0 = st_b + 4 * g;
        int vals[4];
        #pragma unroll
        for (int k = 0; k < 4; k++) {
            int j = j0 + k;
            int widx = j >> 6, r = j & 63;
            u64 w = swords[widx];
            int i = base + j;
            if ((w >> r) & 1) {
                int pos = bo + wpre[widx] + __popcll(w & ((1ull << r) - 1));
                vals[k] = pos;
                skel[pos - bo + selpad] = i;
            } else {
                vals[k] = (i >= bval) ? rep1 : rep0;
            }
        }
        *(int4*)(back_out + base + j0) = make_int4(vals[0], vals[1], vals[2], vals[3]);
    }
    // edges of back region (<=3 head, <=3 tail)
    for (int j = threadIdx.x; j < st_b; j += BLOCK) {
        int widx = j >> 6, r = j & 63;
        u64 w = swords[widx];
        int i = base + j, val;
        if ((w >> r) & 1) {
            int pos = bo + wpre[widx] + __popcll(w & ((1ull << r) - 1));
            val = pos;
            skel[pos - bo + selpad] = i;
        } else val = (i >= bval) ? rep1 : rep0;
        back_out[i] = val;
    }
    for (int j = st_b + 4 * ngroups + threadIdx.x; j < lim; j += BLOCK) {
        int widx = j >> 6, r = j & 63;
        u64 w = swords[widx];
        int i = base + j, val;
        if ((w >> r) & 1) {
            int pos = bo + wpre[widx] + __popcll(w & ((1ull << r) - 1));
            val = pos;
            skel[pos - bo + selpad] = i;
        } else val = (i >= bval) ? rep1 : rep0;
        back_out[i] = val;
    }
    __syncthreads();
    // sel_out: aligned int4 stores fed by aligned ds_read_b128
    int nvg = (tot - st_s) >> 2;
    for (int g = threadIdx.x; g < nvg; g += BLOCK) {
        int4 v = *(const int4*)&skel[4 + 4 * g];
        *(int4*)(sel_out + bo + st_s + 4 * g) = v;
    }
    for (int j = threadIdx.x; j < st_s; j += BLOCK) sel_out[bo + j] = skel[j + selpad];
    for (int j = st_s + 4 * nvg + threadIdx.x; j < tot; j += BLOCK) sel_out[bo + j] = skel[j + selpad];
}

extern "C" void kernel_launch(void* const* d_in, const int* in_sizes, int n_in,
                              void* d_out, int out_size, void* d_ws, size_t ws_size,
                              hipStream_t stream) {
    const float* score = (const float*)d_in[0];
    const int* row_splits = (const int*)d_in[1];
    int n = in_sizes[0];
    int n_seg = in_sizes[1] - 1;
    int M = out_size - (n_seg + 1) - n;
    int nb = (n + TILE - 1) / TILE;
    int nwords = (n + 63) / 64;

    u64* seg_packed    = (u64*)d_ws;                      // 64 u64 (written by k_scanq)
    int4* partial_pack = (int4*)(seg_packed + MAXSEG);    // 2*nb int4 (16B aligned)
    int* block_counts  = (int*)(partial_pack + 2 * nb);   // nb int
    int* block_offsets = block_counts + nb;               // nb int
    int* rep_pos       = block_offsets + nb;              // 64 int
    uintptr_t bm_addr  = (uintptr_t)(rep_pos + MAXSEG);
    bm_addr = (bm_addr + 7) & ~(uintptr_t)7;
    u64* bitmask       = (u64*)bm_addr;                   // nwords u64

    int* out = (int*)d_out;
    int* sel_out   = out;
    int* newrs_out = out + M;
    int* back_out  = out + M + (n_seg + 1);

    // 3 dispatches, zero workspace init, zero global atomics
    hipLaunchKernelGGL(k_pass1, dim3(nb), dim3(BLOCK), 0, stream,
                       score, row_splits, n_seg, n, nwords,
                       partial_pack, bitmask, block_counts);
    hipLaunchKernelGGL(k_scanq, dim3(1), dim3(BT), 0, stream,
                       block_counts, block_offsets, nb,
                       row_splits, n_seg, n, M,
                       partial_pack, seg_packed, bitmask, rep_pos, newrs_out);
    hipLaunchKernelGGL(k_output, dim3(nb), dim3(BLOCK), 0, stream,
                       score, row_splits, n_seg, n,
                       partial_pack, seg_packed,
                       rep_pos, bitmask, block_offsets,
                       sel_out, back_out);
}

// Round 9
// 170.469 us; speedup vs baseline: 1.3721x; 1.1397x over previous
//
#include <hip/hip_runtime.h>
#include <stdint.h>

#define BLOCK 256
#define ITEMS 8
#define TILE (BLOCK * ITEMS)   // 2048 elements per block
#define WPB (TILE / 64)        // 32 bitmask words per block
#define MAXSEG 64
#define BT 1024                // k_scanq block size (16 waves: latency hiding, R7/R8 lesson)
#define THRESH 0.1f

typedef unsigned long long u64;

__device__ __forceinline__ int find_seg(const int* rs, int n_seg, int i) {
    // largest s with rs[s] <= i
    int lo = 0, hi = n_seg;
    while (hi - lo > 1) {
        int mid = (lo + hi) >> 1;
        if (rs[mid] <= i) lo = mid; else hi = mid;
    }
    return lo;
}

// Pass 1 (R0 champion body, byte-identical): single read of score producing
//   - threshold keep-bitmask (s > THRESH)  [min-tied bits fixed up in k_segfix]
//   - per-block keep counts (threshold-only; fixed up in k_segfix)
//   - per-block packed (min_bits<<32 | idx) partials, <=2 segments per block
__global__ __launch_bounds__(BLOCK) void k_pass1(const float* __restrict__ score,
        const int* __restrict__ row_splits, int n_seg, int n, int nwords,
        u64* __restrict__ partial_val, int* __restrict__ partial_seg,
        u64* __restrict__ bitmask, int* __restrict__ block_counts) {
    __shared__ int rs[MAXSEG + 1];
    __shared__ u64 wval[8];
    __shared__ int wseg[8];
    __shared__ int wsum[4];
    for (int j = threadIdx.x; j <= n_seg; j += BLOCK) rs[j] = row_splits[j];
    __syncthreads();
    int lane = threadIdx.x & 63, wv = threadIdx.x >> 6;
    int wbase = blockIdx.x * TILE + wv * 512;
    u64 m0 = ~0ull, m1 = ~0ull;
    int sf = -1, sl = -1, cnt = 0;
    if (wbase < n) {   // wave-uniform
        int wend = min(n, wbase + 512) - 1;
        sf = find_seg(rs, n_seg, wbase);
        sl = find_seg(rs, n_seg, wend);
        int bval = (sl != sf) ? rs[sf + 1] : 0x7FFFFFFF;
        int tbase = wbase + lane * 8;
        unsigned int kbyte = 0;
        if (tbase < n) {
            float v[8];
            if (tbase + 8 <= n) {
                float4 f0 = *(const float4*)(score + tbase);
                float4 f1 = *(const float4*)(score + tbase + 4);
                v[0]=f0.x; v[1]=f0.y; v[2]=f0.z; v[3]=f0.w;
                v[4]=f1.x; v[5]=f1.y; v[6]=f1.z; v[7]=f1.w;
            } else {
                for (int j = 0; j < 8; j++) v[j] = (tbase + j < n) ? score[tbase + j] : 1.0f;
            }
            #pragma unroll
            for (int j = 0; j < 8; j++) {
                int i = tbase + j;
                if (i < n) {
                    u64 p = ((u64)__float_as_uint(v[j]) << 32) | (unsigned int)i;
                    if (i < bval) m0 = min(m0, p); else m1 = min(m1, p);
                    if (v[j] > THRESH) kbyte |= 1u << j;
                }
            }
            cnt = __popc(kbyte);
        }
        // assemble 64-bit words within groups of 8 lanes
        u64 acc = ((u64)kbyte) << (8 * (lane & 7));
        acc |= __shfl_xor((unsigned long long)acc, 1, 64);
        acc |= __shfl_xor((unsigned long long)acc, 2, 64);
        acc |= __shfl_xor((unsigned long long)acc, 4, 64);
        int src = (lane < 8) ? (8 * lane) : lane;
        u64 myword = __shfl((unsigned long long)acc, src, 64);
        for (int o = 32; o > 0; o >>= 1) {
            m0 = min(m0, (u64)__shfl_down((unsigned long long)m0, o, 64));
            m1 = min(m1, (u64)__shfl_down((unsigned long long)m1, o, 64));
            cnt += __shfl_down(cnt, o, 64);
        }
        if (lane < 8) {
            int w = (wbase >> 6) + lane;
            if (w < nwords) bitmask[w] = myword;
        }
    }
    if (lane == 0) {
        wval[2 * wv] = m0;     wseg[2 * wv] = sf;
        wval[2 * wv + 1] = m1; wseg[2 * wv + 1] = (sl != sf) ? sl : -1;
        wsum[wv] = (wbase < n) ? cnt : 0;
    }
    __syncthreads();
    if (threadIdx.x == 0) {
        int base = blockIdx.x * TILE;
        int endi = min(n, base + TILE) - 1;
        int s0 = find_seg(rs, n_seg, base);
        int s1 = find_seg(rs, n_seg, endi);
        u64 o0 = ~0ull, o1 = ~0ull;
        for (int k = 0; k < 8; k++) {
            if (wseg[k] == s0) o0 = min(o0, wval[k]);
            else if (wseg[k] == s1) o1 = min(o1, wval[k]);
        }
        partial_val[2 * blockIdx.x] = o0;
        partial_seg[2 * blockIdx.x] = s0;
        partial_val[2 * blockIdx.x + 1] = o1;
        partial_seg[2 * blockIdx.x + 1] = (s1 != s0) ? s1 : -1;
        block_counts[blockIdx.x] = wsum[0] + wsum[1] + wsum[2] + wsum[3];
    }
}

// Pass 2 (R0 champion body, byte-identical): one block PER SEGMENT: reduce
// block partials -> seg_packed[s]; if segmin <= THRESH, set keep bits for
// min-tied elements (re-reads only the matched ~2048-elem tiles).
__global__ __launch_bounds__(BLOCK) void k_segfix(const float* __restrict__ score,
        const int* __restrict__ row_splits, int n_seg, int n,
        const u64* __restrict__ partial_val, const int* __restrict__ partial_seg,
        u64* __restrict__ seg_packed, u64* __restrict__ bitmask,
        int* __restrict__ block_counts) {
    __shared__ u64 wred[4];
    __shared__ int nmatch;
    __shared__ int mlist[64];
    int s = blockIdx.x;
    int lo = row_splits[s], hi = row_splits[s + 1];
    int lane = threadIdx.x & 63, wv = threadIdx.x >> 6;
    if (threadIdx.x == 0) nmatch = 0;
    u64 m = ~0ull;
    int e0 = 0, e1 = -1;
    if (hi > lo) {
        e0 = 2 * (lo / TILE);
        e1 = 2 * ((hi - 1) / TILE) + 1;
        for (int e = e0 + threadIdx.x; e <= e1; e += BLOCK)
            if (partial_seg[e] == s) m = min(m, partial_val[e]);
    }
    for (int o = 32; o > 0; o >>= 1)
        m = min(m, (u64)__shfl_down((unsigned long long)m, o, 64));
    if (lane == 0) wred[wv] = m;
    __syncthreads();
    if (threadIdx.x == 0) {
        u64 r = min(min(wred[0], wred[1]), min(wred[2], wred[3]));
        wred[0] = r;
        seg_packed[s] = r;
    }
    __syncthreads();
    u64 sp = wred[0];
    if (sp == ~0ull) return;
    unsigned int smb = (unsigned int)(sp >> 32);
    if (__uint_as_float(smb) > THRESH) return;   // threshold bit already covers min elems
    for (int e = e0 + threadIdx.x; e <= e1; e += BLOCK) {
        if (partial_seg[e] == s && (unsigned int)(partial_val[e] >> 32) == smb) {
            int k = atomicAdd(&nmatch, 1);   // LDS atomic, rare
            if (k < 64) mlist[k] = e >> 1;
        }
    }
    __syncthreads();
    int nm = min(nmatch, 64);
    for (int k = 0; k < nm; k++) {
        int b = mlist[k];
        int rlo = max(b * TILE, lo);
        int rhi = min(min((b + 1) * TILE, n), hi);
        int c = 0;
        for (int i = rlo + threadIdx.x; i < rhi; i += BLOCK) {
            if (__float_as_uint(score[i]) == smb) {
                atomicOr(&bitmask[i >> 6], 1ull << (i & 63));
                c++;
            }
        }
        for (int o = 32; o > 0; o >>= 1) c += __shfl_down(c, o, 64);
        if (lane == 0 && c) atomicAdd(&block_counts[b], c);
    }
}

// Pass 3 (R0 logic, BT=1024): exclusive scan of block counts -> block_offsets,
// THEN per-thread queries (newrs + rep_pos) via <=32 bitmask popcounts each.
// ONLY change vs the 173.3 champion: 256 -> 1024 threads. R7 measured this
// kernel class at 76us / VALUBusy 0.013% (pure load latency, 1 block); 16
// waves cut per-thread serial loads 25->7 and quadruple latency hiding.
__global__ __launch_bounds__(BT) void k_scanq(const int* __restrict__ counts,
        int* __restrict__ offsets, int nb,
        const int* __restrict__ row_splits, int n_seg, int n, int M,
        const u64* __restrict__ seg_packed, const u64* __restrict__ bitmask,
        int* __restrict__ rep_pos, int* __restrict__ newrs_out) {
    __shared__ int wtot[BT / 64];
    int lane = threadIdx.x & 63, wv = threadIdx.x >> 6;
    {
        int per = (nb + BT - 1) / BT;
        int s = per * threadIdx.x, e = min(nb, s + per);
        int sum = 0;
        for (int i = s; i < e; i++) sum += counts[i];
        int incl = sum;
        for (int o = 1; o < 64; o <<= 1) {
            int t = __shfl_up(incl, o, 64);
            if (lane >= o) incl += t;
        }
        if (lane == 63) wtot[wv] = incl;
        __syncthreads();
        int excl = incl - sum;
        for (int k = 0; k < wv; k++) excl += wtot[k];
        for (int i = s; i < e; i++) { offsets[i] = excl; excl += counts[i]; }
    }
    __syncthreads();
    int nq = 2 * n_seg + 1;
    int q = threadIdx.x;
    if (q < nq) {
        unsigned int uidx;
        if (q <= n_seg) uidx = (unsigned int)row_splits[q];
        else uidx = (unsigned int)(seg_packed[q - (n_seg + 1)] & 0xFFFFFFFFu);
        int result;
        if (uidx >= (unsigned int)n) {
            result = M;
        } else {
            int idx = (int)uidx;
            int b = idx / TILE;
            int wq = idx >> 6;
            int cnt = offsets[b];
            for (int w = b * WPB; w < wq; w++) cnt += __popcll(bitmask[w]);
            if (idx & 63) cnt += __popcll(bitmask[wq] & ((1ull << (idx & 63)) - 1));
            result = cnt;
        }
        if (q <= n_seg) newrs_out[q] = result;
        else rep_pos[q - (n_seg + 1)] = result;
    }
}

// Pass 4 (R0 champion body, byte-identical): outputs from bitmask. back values
// computed in registers for 4 consecutive phase-aligned positions -> dwordx4
// stores. sel indices staged in LDS with slot offset so vector reads are
// aligned ds_read_b128 (conflict-free). Assumes <=1 segment boundary per
// 2048-elem block (seg len >> 2048 here).
__global__ __launch_bounds__(BLOCK) void k_output(const int* __restrict__ row_splits,
        int n_seg, int n,
        const int* __restrict__ rep_pos, const u64* __restrict__ bitmask,
        const int* __restrict__ block_offsets,
        int* __restrict__ sel_out, int* __restrict__ back_out) {
    __shared__ int rs[MAXSEG + 1];
    __shared__ u64 swords[WPB];
    __shared__ int wpre[WPB];
    __shared__ int shead[6];   // bval, rep0, rep1, tot
    __shared__ alignas(16) int skel[TILE + 8];
    for (int j = threadIdx.x; j <= n_seg; j += BLOCK) rs[j] = row_splits[j];
    int base = blockIdx.x * TILE;
    int lim = min(TILE, n - base);
    int nw = (lim + 63) >> 6;
    for (int j = threadIdx.x; j < nw; j += BLOCK) swords[j] = bitmask[(base >> 6) + j];
    __syncthreads();
    if (threadIdx.x == 0) {
        int acc = 0;
        for (int k = 0; k < nw; k++) { wpre[k] = acc; acc += __popcll(swords[k]); }
        int s0 = find_seg(rs, n_seg, base);
        int s1 = find_seg(rs, n_seg, base + lim - 1);
        shead[0] = (s1 != s0) ? rs[s0 + 1] : 0x7FFFFFFF;
        shead[1] = rep_pos[s0];
        shead[2] = rep_pos[s1];
        shead[3] = acc;
    }
    __syncthreads();
    int bval = shead[0], rep0 = shead[1], rep1 = shead[2], tot = shead[3];
    int bo = block_offsets[blockIdx.x];
    // phases
    int st_b = (int)((4 - ((((uintptr_t)(back_out + base)) >> 2) & 3)) & 3);
    if (st_b > lim) st_b = lim;
    int st_s = (int)((4 - ((((uintptr_t)(sel_out + bo)) >> 2) & 3)) & 3);
    if (st_s > tot) st_s = tot;
    int selpad = 4 - st_s;          // skel slot = (pos - bo) + selpad; first aligned slot = 4

    // main: full int4 groups of back_out; also stage kept indices into skel
    int ngroups = (lim - st_b) >> 2;
    for (int g = threadIdx.x; g < ngroups; g += BLOCK) {
        int j0 = st_b + 4 * g;
        int vals[4];
        #pragma unroll
        for (int k = 0; k < 4; k++) {
            int j = j0 + k;
            int widx = j >> 6, r = j & 63;
            u64 w = swords[widx];
            int i = base + j;
            if ((w >> r) & 1) {
                int pos = bo + wpre[widx] + __popcll(w & ((1ull << r) - 1));
                vals[k] = pos;
                skel[pos - bo + selpad] = i;
            } else {
                vals[k] = (i >= bval) ? rep1 : rep0;
            }
        }
        *(int4*)(back_out + base + j0) = make_int4(vals[0], vals[1], vals[2], vals[3]);
    }
    // edges of back region (<=3 head, <=3 tail)
    for (int j = threadIdx.x; j < st_b; j += BLOCK) {
        int widx = j >> 6, r = j & 63;
        u64 w = swords[widx];
        int i = base + j, val;
        if ((w >> r) & 1) {
            int pos = bo + wpre[widx] + __popcll(w & ((1ull << r) - 1));
            val = pos;
            skel[pos - bo + selpad] = i;
        } else val = (i >= bval) ? rep1 : rep0;
        back_out[i] = val;
    }
    for (int j = st_b + 4 * ngroups + threadIdx.x; j < lim; j += BLOCK) {
        int widx = j >> 6, r = j & 63;
        u64 w = swords[widx];
        int i = base + j, val;
        if ((w >> r) & 1) {
            int pos = bo + wpre[widx] + __popcll(w & ((1ull << r) - 1));
            val = pos;
            skel[pos - bo + selpad] = i;
        } else val = (i >= bval) ? rep1 : rep0;
        back_out[i] = val;
    }
    __syncthreads();
    // sel_out: aligned int4 stores fed by aligned ds_read_b128
    int nvg = (tot - st_s) >> 2;
    for (int g = threadIdx.x; g < nvg; g += BLOCK) {
        int4 v = *(const int4*)&skel[4 + 4 * g];
        *(int4*)(sel_out + bo + st_s + 4 * g) = v;
    }
    for (int j = threadIdx.x; j < st_s; j += BLOCK) sel_out[bo + j] = skel[j + selpad];
    for (int j = st_s + 4 * nvg + threadIdx.x; j < tot; j += BLOCK) sel_out[bo + j] = skel[j + selpad];
}

extern "C" void kernel_launch(void* const* d_in, const int* in_sizes, int n_in,
                              void* d_out, int out_size, void* d_ws, size_t ws_size,
                              hipStream_t stream) {
    const float* score = (const float*)d_in[0];
    const int* row_splits = (const int*)d_in[1];
    int n = in_sizes[0];
    int n_seg = in_sizes[1] - 1;
    int M = out_size - (n_seg + 1) - n;
    int nb = (n + TILE - 1) / TILE;
    int nwords = (n + 63) / 64;

    u64* seg_packed   = (u64*)d_ws;                      // 64 u64
    u64* partial_val  = seg_packed + MAXSEG;             // 2*nb u64
    int* partial_seg  = (int*)(partial_val + 2 * nb);    // 2*nb int
    int* rep_pos      = partial_seg + 2 * nb;            // 64 int
    int* block_counts = rep_pos + 64;                    // nb int
    int* block_offsets= block_counts + nb;               // nb int
    uintptr_t bm_addr = (uintptr_t)(block_offsets + nb);
    bm_addr = (bm_addr + 7) & ~(uintptr_t)7;
    u64* bitmask      = (u64*)bm_addr;                   // nwords u64

    int* out = (int*)d_out;
    int* sel_out   = out;
    int* newrs_out = out + M;
    int* back_out  = out + M + (n_seg + 1);

    hipLaunchKernelGGL(k_pass1, dim3(nb), dim3(BLOCK), 0, stream,
                       score, row_splits, n_seg, n, nwords,
                       partial_val, partial_seg, bitmask, block_counts);
    hipLaunchKernelGGL(k_segfix, dim3(n_seg), dim3(BLOCK), 0, stream,
                       score, row_splits, n_seg, n,
                       partial_val, partial_seg, seg_packed, bitmask, block_counts);
    hipLaunchKernelGGL(k_scanq, dim3(1), dim3(BT), 0, stream,
                       block_counts, block_offsets, nb,
                       row_splits, n_seg, n, M, seg_packed, bitmask,
                       rep_pos, newrs_out);
    hipLaunchKernelGGL(k_output, dim3(nb), dim3(BLOCK), 0, stream,
                       row_splits, n_seg, n, rep_pos, bitmask,
                       block_offsets, sel_out, back_out);
}

// Round 10
// 167.328 us; speedup vs baseline: 1.3979x; 1.0188x over previous
//
#include <hip/hip_runtime.h>
#include <stdint.h>

#define BLOCK 256
#define ITEMS 8
#define TILE (BLOCK * ITEMS)   // 2048 elements per block
#define WPB (TILE / 64)        // 32 bitmask words per block
#define MAXSEG 64
#define BT 1024                // k_scanq block size (16 waves: latency hiding, R7/R9 lesson)
#define THRESH 0.1f

typedef unsigned long long u64;

__device__ __forceinline__ int find_seg(const int* rs, int n_seg, int i) {
    // largest s with rs[s] <= i
    int lo = 0, hi = n_seg;
    while (hi - lo > 1) {
        int mid = (lo + hi) >> 1;
        if (rs[mid] <= i) lo = mid; else hi = mid;
    }
    return lo;
}

// Pass 1 (R9 champion body, byte-identical): single read of score producing
//   - threshold keep-bitmask (s > THRESH)  [min-tied bits fixed up in k_segfix]
//   - per-block keep counts (threshold-only; fixed up in k_segfix)
//   - per-block packed (min_bits<<32 | idx) partials, <=2 segments per block
__global__ __launch_bounds__(BLOCK) void k_pass1(const float* __restrict__ score,
        const int* __restrict__ row_splits, int n_seg, int n, int nwords,
        u64* __restrict__ partial_val, int* __restrict__ partial_seg,
        u64* __restrict__ bitmask, int* __restrict__ block_counts) {
    __shared__ int rs[MAXSEG + 1];
    __shared__ u64 wval[8];
    __shared__ int wseg[8];
    __shared__ int wsum[4];
    for (int j = threadIdx.x; j <= n_seg; j += BLOCK) rs[j] = row_splits[j];
    __syncthreads();
    int lane = threadIdx.x & 63, wv = threadIdx.x >> 6;
    int wbase = blockIdx.x * TILE + wv * 512;
    u64 m0 = ~0ull, m1 = ~0ull;
    int sf = -1, sl = -1, cnt = 0;
    if (wbase < n) {   // wave-uniform
        int wend = min(n, wbase + 512) - 1;
        sf = find_seg(rs, n_seg, wbase);
        sl = find_seg(rs, n_seg, wend);
        int bval = (sl != sf) ? rs[sf + 1] : 0x7FFFFFFF;
        int tbase = wbase + lane * 8;
        unsigned int kbyte = 0;
        if (tbase < n) {
            float v[8];
            if (tbase + 8 <= n) {
                float4 f0 = *(const float4*)(score + tbase);
                float4 f1 = *(const float4*)(score + tbase + 4);
                v[0]=f0.x; v[1]=f0.y; v[2]=f0.z; v[3]=f0.w;
                v[4]=f1.x; v[5]=f1.y; v[6]=f1.z; v[7]=f1.w;
            } else {
                for (int j = 0; j < 8; j++) v[j] = (tbase + j < n) ? score[tbase + j] : 1.0f;
            }
            #pragma unroll
            for (int j = 0; j < 8; j++) {
                int i = tbase + j;
                if (i < n) {
                    u64 p = ((u64)__float_as_uint(v[j]) << 32) | (unsigned int)i;
                    if (i < bval) m0 = min(m0, p); else m1 = min(m1, p);
                    if (v[j] > THRESH) kbyte |= 1u << j;
                }
            }
            cnt = __popc(kbyte);
        }
        // assemble 64-bit words within groups of 8 lanes
        u64 acc = ((u64)kbyte) << (8 * (lane & 7));
        acc |= __shfl_xor((unsigned long long)acc, 1, 64);
        acc |= __shfl_xor((unsigned long long)acc, 2, 64);
        acc |= __shfl_xor((unsigned long long)acc, 4, 64);
        int src = (lane < 8) ? (8 * lane) : lane;
        u64 myword = __shfl((unsigned long long)acc, src, 64);
        for (int o = 32; o > 0; o >>= 1) {
            m0 = min(m0, (u64)__shfl_down((unsigned long long)m0, o, 64));
            m1 = min(m1, (u64)__shfl_down((unsigned long long)m1, o, 64));
            cnt += __shfl_down(cnt, o, 64);
        }
        if (lane < 8) {
            int w = (wbase >> 6) + lane;
            if (w < nwords) bitmask[w] = myword;
        }
    }
    if (lane == 0) {
        wval[2 * wv] = m0;     wseg[2 * wv] = sf;
        wval[2 * wv + 1] = m1; wseg[2 * wv + 1] = (sl != sf) ? sl : -1;
        wsum[wv] = (wbase < n) ? cnt : 0;
    }
    __syncthreads();
    if (threadIdx.x == 0) {
        int base = blockIdx.x * TILE;
        int endi = min(n, base + TILE) - 1;
        int s0 = find_seg(rs, n_seg, base);
        int s1 = find_seg(rs, n_seg, endi);
        u64 o0 = ~0ull, o1 = ~0ull;
        for (int k = 0; k < 8; k++) {
            if (wseg[k] == s0) o0 = min(o0, wval[k]);
            else if (wseg[k] == s1) o1 = min(o1, wval[k]);
        }
        partial_val[2 * blockIdx.x] = o0;
        partial_seg[2 * blockIdx.x] = s0;
        partial_val[2 * blockIdx.x + 1] = o1;
        partial_seg[2 * blockIdx.x + 1] = (s1 != s0) ? s1 : -1;
        block_counts[blockIdx.x] = wsum[0] + wsum[1] + wsum[2] + wsum[3];
    }
}

// Pass 2 (R9 champion body, byte-identical): one block PER SEGMENT: reduce
// block partials -> seg_packed[s]; if segmin <= THRESH, set keep bits for
// min-tied elements (re-reads only the matched ~2048-elem tiles).
__global__ __launch_bounds__(BLOCK) void k_segfix(const float* __restrict__ score,
        const int* __restrict__ row_splits, int n_seg, int n,
        const u64* __restrict__ partial_val, const int* __restrict__ partial_seg,
        u64* __restrict__ seg_packed, u64* __restrict__ bitmask,
        int* __restrict__ block_counts) {
    __shared__ u64 wred[4];
    __shared__ int nmatch;
    __shared__ int mlist[64];
    int s = blockIdx.x;
    int lo = row_splits[s], hi = row_splits[s + 1];
    int lane = threadIdx.x & 63, wv = threadIdx.x >> 6;
    if (threadIdx.x == 0) nmatch = 0;
    u64 m = ~0ull;
    int e0 = 0, e1 = -1;
    if (hi > lo) {
        e0 = 2 * (lo / TILE);
        e1 = 2 * ((hi - 1) / TILE) + 1;
        for (int e = e0 + threadIdx.x; e <= e1; e += BLOCK)
            if (partial_seg[e] == s) m = min(m, partial_val[e]);
    }
    for (int o = 32; o > 0; o >>= 1)
        m = min(m, (u64)__shfl_down((unsigned long long)m, o, 64));
    if (lane == 0) wred[wv] = m;
    __syncthreads();
    if (threadIdx.x == 0) {
        u64 r = min(min(wred[0], wred[1]), min(wred[2], wred[3]));
        wred[0] = r;
        seg_packed[s] = r;
    }
    __syncthreads();
    u64 sp = wred[0];
    if (sp == ~0ull) return;
    unsigned int smb = (unsigned int)(sp >> 32);
    if (__uint_as_float(smb) > THRESH) return;   // threshold bit already covers min elems
    for (int e = e0 + threadIdx.x; e <= e1; e += BLOCK) {
        if (partial_seg[e] == s && (unsigned int)(partial_val[e] >> 32) == smb) {
            int k = atomicAdd(&nmatch, 1);   // LDS atomic, rare
            if (k < 64) mlist[k] = e >> 1;
        }
    }
    __syncthreads();
    int nm = min(nmatch, 64);
    for (int k = 0; k < nm; k++) {
        int b = mlist[k];
        int rlo = max(b * TILE, lo);
        int rhi = min(min((b + 1) * TILE, n), hi);
        int c = 0;
        for (int i = rlo + threadIdx.x; i < rhi; i += BLOCK) {
            if (__float_as_uint(score[i]) == smb) {
                atomicOr(&bitmask[i >> 6], 1ull << (i & 63));
                c++;
            }
        }
        for (int o = 32; o > 0; o >>= 1) c += __shfl_down(c, o, 64);
        if (lane == 0 && c) atomicAdd(&block_counts[b], c);
    }
}

// Pass 3 (R9 champion body, byte-identical; BT=1024): exclusive scan of block
// counts -> block_offsets, THEN per-thread queries (newrs + rep_pos) via <=32
// bitmask popcounts each.
__global__ __launch_bounds__(BT) void k_scanq(const int* __restrict__ counts,
        int* __restrict__ offsets, int nb,
        const int* __restrict__ row_splits, int n_seg, int n, int M,
        const u64* __restrict__ seg_packed, const u64* __restrict__ bitmask,
        int* __restrict__ rep_pos, int* __restrict__ newrs_out) {
    __shared__ int wtot[BT / 64];
    int lane = threadIdx.x & 63, wv = threadIdx.x >> 6;
    {
        int per = (nb + BT - 1) / BT;
        int s = per * threadIdx.x, e = min(nb, s + per);
        int sum = 0;
        for (int i = s; i < e; i++) sum += counts[i];
        int incl = sum;
        for (int o = 1; o < 64; o <<= 1) {
            int t = __shfl_up(incl, o, 64);
            if (lane >= o) incl += t;
        }
        if (lane == 63) wtot[wv] = incl;
        __syncthreads();
        int excl = incl - sum;
        for (int k = 0; k < wv; k++) excl += wtot[k];
        for (int i = s; i < e; i++) { offsets[i] = excl; excl += counts[i]; }
    }
    __syncthreads();
    int nq = 2 * n_seg + 1;
    int q = threadIdx.x;
    if (q < nq) {
        unsigned int uidx;
        if (q <= n_seg) uidx = (unsigned int)row_splits[q];
        else uidx = (unsigned int)(seg_packed[q - (n_seg + 1)] & 0xFFFFFFFFu);
        int result;
        if (uidx >= (unsigned int)n) {
            result = M;
        } else {
            int idx = (int)uidx;
            int b = idx / TILE;
            int wq = idx >> 6;
            int cnt = offsets[b];
            for (int w = b * WPB; w < wq; w++) cnt += __popcll(bitmask[w]);
            if (idx & 63) cnt += __popcll(bitmask[wq] & ((1ull << (idx & 63)) - 1));
            result = cnt;
        }
        if (q <= n_seg) newrs_out[q] = result;
        else rep_pos[q - (n_seg + 1)] = result;
    }
}

// Pass 4 (R9 body + parallel prologue): the champion's prologue was a
// thread0-serial chain (32-word wpre loop -> find_seg x2 -> 2 dependent
// rep_pos loads) + a post-barrier block_offsets broadcast load: ~2000
// serialized cycles/block. Now split across waves so latency = max, not sum:
//   wave 0 lanes 0..31: parallel wpre (popcount + shfl inclusive scan) + tot
//   thread 64:          find_seg -> bval; rep_pos[s0], rep_pos[s1]
//   thread 128:         block_offsets[bid] -> shead[4]
// Output body below is byte-identical to the champion.
__global__ __launch_bounds__(BLOCK) void k_output(const int* __restrict__ row_splits,
        int n_seg, int n,
        const int* __restrict__ rep_pos, const u64* __restrict__ bitmask,
        const int* __restrict__ block_offsets,
        int* __restrict__ sel_out, int* __restrict__ back_out) {
    __shared__ int rs[MAXSEG + 1];
    __shared__ u64 swords[WPB];
    __shared__ int wpre[WPB];
    __shared__ int shead[6];   // bval, rep0, rep1, tot, bo
    __shared__ alignas(16) int skel[TILE + 8];
    // issue the independent block_offsets load immediately (hides under staging)
    if (threadIdx.x == 128) shead[4] = block_offsets[blockIdx.x];
    for (int j = threadIdx.x; j <= n_seg; j += BLOCK) rs[j] = row_splits[j];
    int base = blockIdx.x * TILE;
    int lim = min(TILE, n - base);
    int nw = (lim + 63) >> 6;
    for (int j = threadIdx.x; j < nw; j += BLOCK) swords[j] = bitmask[(base >> 6) + j];
    __syncthreads();
    int lane = threadIdx.x & 63, wv = threadIdx.x >> 6;
    if (wv == 0) {
        // parallel wpre: lane i popcounts word i, 6-step inclusive shfl scan
        int pc = (lane < nw) ? (int)__popcll(swords[lane]) : 0;
        int incl = pc;
        for (int o = 1; o < 32; o <<= 1) {
            int t = __shfl_up(incl, o, 64);
            if (lane >= o) incl += t;
        }
        if (lane < nw) wpre[lane] = incl - pc;
        int tot = __shfl(incl, nw - 1, 64);
        if (lane == 0) shead[3] = tot;
    } else if (threadIdx.x == 64) {
        int s0 = find_seg(rs, n_seg, base);
        int s1 = find_seg(rs, n_seg, base + lim - 1);
        shead[0] = (s1 != s0) ? rs[s0 + 1] : 0x7FFFFFFF;
        shead[1] = rep_pos[s0];
        shead[2] = rep_pos[s1];
    }
    __syncthreads();
    int bval = shead[0], rep0 = shead[1], rep1 = shead[2], tot = shead[3];
    int bo = shead[4];
    // phases
    int st_b = (int)((4 - ((((uintptr_t)(back_out + base)) >> 2) & 3)) & 3);
    if (st_b > lim) st_b = lim;
    int st_s = (int)((4 - ((((uintptr_t)(sel_out + bo)) >> 2) & 3)) & 3);
    if (st_s > tot) st_s = tot;
    int selpad = 4 - st_s;          // skel slot = (pos - bo) + selpad; first aligned slot = 4

    // main: full int4 groups of back_out; also stage kept indices into skel
    int ngroups = (lim - st_b) >> 2;
    for (int g = threadIdx.x; g < ngroups; g += BLOCK) {
        int j0 = st_b + 4 * g;
        int vals[4];
        #pragma unroll
        for (int k = 0; k < 4; k++) {
            int j = j0 + k;
            int widx = j >> 6, r = j & 63;
            u64 w = swords[widx];
            int i = base + j;
            if ((w >> r) & 1) {
                int pos = bo + wpre[widx] + __popcll(w & ((1ull << r) - 1));
                vals[k] = pos;
                skel[pos - bo + selpad] = i;
            } else {
                vals[k] = (i >= bval) ? rep1 : rep0;
            }
        }
        *(int4*)(back_out + base + j0) = make_int4(vals[0], vals[1], vals[2], vals[3]);
    }
    // edges of back region (<=3 head, <=3 tail)
    for (int j = threadIdx.x; j < st_b; j += BLOCK) {
        int widx = j >> 6, r = j & 63;
        u64 w = swords[widx];
        int i = base + j, val;
        if ((w >> r) & 1) {
            int pos = bo + wpre[widx] + __popcll(w & ((1ull << r) - 1));
            val = pos;
            skel[pos - bo + selpad] = i;
        } else val = (i >= bval) ? rep1 : rep0;
        back_out[i] = val;
    }
    for (int j = st_b + 4 * ngroups + threadIdx.x; j < lim; j += BLOCK) {
        int widx = j >> 6, r = j & 63;
        u64 w = swords[widx];
        int i = base + j, val;
        if ((w >> r) & 1) {
            int pos = bo + wpre[widx] + __popcll(w & ((1ull << r) - 1));
            val = pos;
            skel[pos - bo + selpad] = i;
        } else val = (i >= bval) ? rep1 : rep0;
        back_out[i] = val;
    }
    __syncthreads();
    // sel_out: aligned int4 stores fed by aligned ds_read_b128
    int nvg = (tot - st_s) >> 2;
    for (int g = threadIdx.x; g < nvg; g += BLOCK) {
        int4 v = *(const int4*)&skel[4 + 4 * g];
        *(int4*)(sel_out + bo + st_s + 4 * g) = v;
    }
    for (int j = threadIdx.x; j < st_s; j += BLOCK) sel_out[bo + j] = skel[j + selpad];
    for (int j = st_s + 4 * nvg + threadIdx.x; j < tot; j += BLOCK) sel_out[bo + j] = skel[j + selpad];
}

extern "C" void kernel_launch(void* const* d_in, const int* in_sizes, int n_in,
                              void* d_out, int out_size, void* d_ws, size_t ws_size,
                              hipStream_t stream) {
    const float* score = (const float*)d_in[0];
    const int* row_splits = (const int*)d_in[1];
    int n = in_sizes[0];
    int n_seg = in_sizes[1] - 1;
    int M = out_size - (n_seg + 1) - n;
    int nb = (n + TILE - 1) / TILE;
    int nwords = (n + 63) / 64;

    u64* seg_packed   = (u64*)d_ws;                      // 64 u64
    u64* partial_val  = seg_packed + MAXSEG;             // 2*nb u64
    int* partial_seg  = (int*)(partial_val + 2 * nb);    // 2*nb int
    int* rep_pos      = partial_seg + 2 * nb;            // 64 int
    int* block_counts = rep_pos + 64;                    // nb int
    int* block_offsets= block_counts + nb;               // nb int
    uintptr_t bm_addr = (uintptr_t)(block_offsets + nb);
    bm_addr = (bm_addr + 7) & ~(uintptr_t)7;
    u64* bitmask      = (u64*)bm_addr;                   // nwords u64

    int* out = (int*)d_out;
    int* sel_out   = out;
    int* newrs_out = out + M;
    int* back_out  = out + M + (n_seg + 1);

    hipLaunchKernelGGL(k_pass1, dim3(nb), dim3(BLOCK), 0, stream,
                       score, row_splits, n_seg, n, nwords,
                       partial_val, partial_seg, bitmask, block_counts);
    hipLaunchKernelGGL(k_segfix, dim3(n_seg), dim3(BLOCK), 0, stream,
                       score, row_splits, n_seg, n,
                       partial_val, partial_seg, seg_packed, bitmask, block_counts);
    hipLaunchKernelGGL(k_scanq, dim3(1), dim3(BT), 0, stream,
                       block_counts, block_offsets, nb,
                       row_splits, n_seg, n, M, seg_packed, bitmask,
                       rep_pos, newrs_out);
    hipLaunchKernelGGL(k_output, dim3(nb), dim3(BLOCK), 0, stream,
                       row_splits, n_seg, n, rep_pos, bitmask,
                       block_offsets, sel_out, back_out);
}